// Round 3
// baseline (2710.990 us; speedup 1.0000x reference)
//
#include <hip/hip_runtime.h>
#include <cstdint>
#include <cstddef>

typedef unsigned short ushort_t;
typedef unsigned int uint_t;

#define B_ 16
#define N_ 4096
#define S_ 1024
#define K_ 32
#define NR 524288    // B*S*K rows
#define NQ 16384     // B*S queries
#define NWAVES 8192  // NR / 64

// DT: 1 = bf16 buffers, 0 = fp32 buffers
#define DT_BF16 1
#define DT_FP32 0

__device__ __forceinline__ float bf2f(ushort_t u) {
    union { uint_t i; float f; } x; x.i = ((uint_t)u) << 16; return x.f;
}
__device__ __forceinline__ ushort_t f2bf(float f) {
    union { float f; uint_t u; } x; x.f = f;
    uint_t u = x.u;
    uint_t r = (u + 0x7fffu + ((u >> 16) & 1u)) >> 16;   // RNE
    return (ushort_t)r;
}

template <int DT>
__device__ __forceinline__ float ldx(const void* p, size_t i) {
    if (DT) return bf2f(((const ushort_t*)p)[i]);
    else    return ((const float*)p)[i];
}
template <int DT>
__device__ __forceinline__ void stx(void* p, size_t i, float v) {
    if (DT) ((ushort_t*)p)[i] = f2bf(v);
    else    ((float*)p)[i] = v;
}

// ---------------------------------------------------------------------------
// detect: decide whether inputs are bf16 (flag=1) or fp32 (flag=0).
// bf16 data: every 16-bit half is a bf16 of N(0,1) -> exponent in [118,130].
// fp32 data: low halfword is uniform mantissa bits -> exponent uniform.
// ---------------------------------------------------------------------------
__global__ void detect_kernel(const uint_t* __restrict__ xyz, int* __restrict__ flag) {
    if (threadIdx.x == 0 && blockIdx.x == 0) {
        int hits = 0;
        for (int i = 0; i < 256; i++) {
            uint_t lo = xyz[i] & 0xffffu;
            int e = (int)((lo >> 7) & 0xffu);
            if (e >= 117 && e <= 131) hits++;
        }
        *flag = (hits >= 128) ? 1 : 0;
    }
}

// ---------------------------------------------------------------------------
// prep: weights -> fp32 transposed. wt0[c][64], wt1[c][64], wt2[c][128]
// ---------------------------------------------------------------------------
template <int DT>
__global__ __launch_bounds__(256) void prep_kernel(
        const void* __restrict__ W0, const void* __restrict__ W1,
        const void* __restrict__ W2,
        float* __restrict__ wt0, float* __restrict__ wt1, float* __restrict__ wt2,
        const int* __restrict__ flag) {
    if (*flag != DT) return;
    int tid = threadIdx.x;
    for (int i = tid; i < 64 * 67; i += 256) { int o = i / 67, c = i % 67; wt0[c * 64 + o] = ldx<DT>(W0, i); }
    for (int i = tid; i < 64 * 64; i += 256) { int o = i >> 6, c = i & 63; wt1[c * 64 + o] = ldx<DT>(W1, i); }
    for (int i = tid; i < 128 * 64; i += 256) { int o = i >> 6, c = i & 63; wt2[c * 128 + o] = ldx<DT>(W2, i); }
}

// ---------------------------------------------------------------------------
// FPS: one block per batch. Exact reference arithmetic (no fma contraction),
// argmax tie-break = lowest index.
// ---------------------------------------------------------------------------
template <int DT>
__global__ __launch_bounds__(1024) void fps_kernel(
        const void* __restrict__ xyz, float* __restrict__ qxyz,
        void* __restrict__ out_sxyz, const int* __restrict__ flag) {
    #pragma clang fp contract(off)
    if (*flag != DT) return;
    __shared__ float xs[N_], ys[N_], zs[N_];
    __shared__ float rv[16];
    __shared__ int   ri[16];
    __shared__ int   sfar;
    int b = blockIdx.x, tid = threadIdx.x;
    size_t base = (size_t)b * N_ * 3;

    float px[4], py[4], pz[4], dist[4];
    #pragma unroll
    for (int t = 0; t < 4; t++) {
        int p = tid + t * 1024;
        float x = ldx<DT>(xyz, base + p * 3 + 0);
        float y = ldx<DT>(xyz, base + p * 3 + 1);
        float z = ldx<DT>(xyz, base + p * 3 + 2);
        px[t] = x; py[t] = y; pz[t] = z;
        xs[p] = x; ys[p] = y; zs[p] = z;
        dist[t] = 1e10f;
    }
    __syncthreads();

    int far = 0;
    for (int i = 0; i < S_; i++) {
        float cx = xs[far], cy = ys[far], cz = zs[far];
        if (tid == 0) {
            int qi = b * S_ + i;
            qxyz[qi * 3 + 0] = cx; qxyz[qi * 3 + 1] = cy; qxyz[qi * 3 + 2] = cz;
            stx<DT>(out_sxyz, (size_t)qi * 3 + 0, cx);
            stx<DT>(out_sxyz, (size_t)qi * 3 + 1, cy);
            stx<DT>(out_sxyz, (size_t)qi * 3 + 2, cz);
        }
        float bv = -1.0f; int bi = 0;
        #pragma unroll
        for (int t = 0; t < 4; t++) {
            float dx = px[t] - cx, dy = py[t] - cy, dz = pz[t] - cz;
            float d = (dx * dx + dy * dy) + dz * dz;   // matches ref sum order
            float nd = fminf(dist[t], d);
            dist[t] = nd;
            int p = tid + t * 1024;
            if (nd > bv || (nd == bv && p < bi)) { bv = nd; bi = p; }
        }
        #pragma unroll
        for (int off = 32; off >= 1; off >>= 1) {
            float ov = __shfl_down(bv, off);
            int   oi = __shfl_down(bi, off);
            if (ov > bv || (ov == bv && oi < bi)) { bv = ov; bi = oi; }
        }
        if ((tid & 63) == 0) { rv[tid >> 6] = bv; ri[tid >> 6] = bi; }
        __syncthreads();
        if (tid < 64) {
            float v2 = (tid < 16) ? rv[tid] : -1.0f;
            int   i2 = (tid < 16) ? ri[tid] : 0;
            #pragma unroll
            for (int off = 8; off >= 1; off >>= 1) {
                float ov = __shfl_down(v2, off);
                int   oi = __shfl_down(i2, off);
                if (ov > v2 || (ov == v2 && oi < i2)) { v2 = ov; i2 = oi; }
            }
            if (tid == 0) sfar = i2;
        }
        __syncthreads();
        far = sfar;
    }
}

// ---------------------------------------------------------------------------
// KNN: one wave per query -> 32 neighbor indices. Exact reference distance.
// ---------------------------------------------------------------------------
template <int DT>
__global__ __launch_bounds__(64) void knn_kernel(
        const void* __restrict__ xyz, const float* __restrict__ qxyz,
        int* __restrict__ nbr, const int* __restrict__ flag) {
    #pragma clang fp contract(off)
    if (*flag != DT) return;
    __shared__ float dsm[N_];
    int bs = blockIdx.x;
    int b = bs >> 10;
    int lane = threadIdx.x;
    size_t xb = (size_t)b * N_ * 3;

    float qx = qxyz[bs * 3 + 0], qy = qxyz[bs * 3 + 1], qz = qxyz[bs * 3 + 2];
    float qq = (qx * qx + qy * qy) + qz * qz;

    const float FINF = __builtin_inff();
    float lv = FINF; int li = 0;
    for (int s = 0; s < 64; s++) {
        int p = s * 64 + lane;
        float x = ldx<DT>(xyz, xb + p * 3 + 0);
        float y = ldx<DT>(xyz, xb + p * 3 + 1);
        float z = ldx<DT>(xyz, xb + p * 3 + 2);
        float pp = (x * x + y * y) + z * z;
        float dt = (qx * x + qy * y) + qz * z;
        float d = (qq + pp) - 2.0f * dt;               // matches ref
        dsm[s * 64 + ((lane + s) & 63)] = d;           // swizzled store
        if (d < lv) { lv = d; li = p; }
    }
    __syncthreads();

    unsigned long long mask = 0ull;   // consumed rows of MY column
    int my_nbr = 0;
    for (int r = 0; r < K_; r++) {
        float v = lv; int idx = li;
        #pragma unroll
        for (int off = 32; off >= 1; off >>= 1) {
            float ov = __shfl_down(v, off);
            int   oi = __shfl_down(idx, off);
            if (ov < v || (ov == v && oi < idx)) { v = ov; idx = oi; }
        }
        idx = __shfl(idx, 0);
        int glane = idx & 63;
        if (lane == r) my_nbr = idx;
        if (lane == glane) mask |= 1ull << (idx >> 6);
        unsigned long long gm = __shfl(mask, glane);
        // refresh glane's column min over unconsumed entries (lane = s index)
        float v2 = ((gm >> lane) & 1ull) ? FINF : dsm[lane * 64 + ((glane + lane) & 63)];
        int i2 = lane * 64 + glane;
        #pragma unroll
        for (int off = 32; off >= 1; off >>= 1) {
            float ov = __shfl_down(v2, off);
            int   oi = __shfl_down(i2, off);
            if (ov < v2 || (ov == v2 && oi < i2)) { v2 = ov; i2 = oi; }
        }
        v2 = __shfl(v2, 0); i2 = __shfl(i2, 0);
        if (lane == glane) { lv = v2; li = i2; }
    }
    if (lane < K_) nbr[bs * K_ + lane] = my_nbr;
}

// ---------------------------------------------------------------------------
// L0: one thread per row. Gather xyz-diff + 64 features, y0 = W0 x -> yT bf16.
// ---------------------------------------------------------------------------
template <int DT>
__global__ __launch_bounds__(256) void l0_kernel(
        const void* __restrict__ xyz, const void* __restrict__ fea,
        const float* __restrict__ qxyz, const int* __restrict__ nbr,
        const float* __restrict__ wt0, ushort_t* __restrict__ yT,
        const int* __restrict__ flag) {
    if (*flag != DT) return;
    int row = blockIdx.x * 256 + threadIdx.x;
    int bs = row >> 5, b = bs >> 10;
    int p = nbr[row];
    p = (p < 0) ? 0 : (p > N_ - 1 ? N_ - 1 : p);       // defensive clamp
    float qx = qxyz[bs * 3 + 0], qy = qxyz[bs * 3 + 1], qz = qxyz[bs * 3 + 2];
    size_t xb = ((size_t)b * N_ + p) * 3;
    float dx = ldx<DT>(xyz, xb + 0) - qx;
    float dy = ldx<DT>(xyz, xb + 1) - qy;
    float dz = ldx<DT>(xyz, xb + 2) - qz;

    float acc[64];
    #pragma unroll
    for (int o = 0; o < 64; o++)
        acc[o] = fmaf(dz, wt0[128 + o], fmaf(dy, wt0[64 + o], dx * wt0[o]));

    size_t fb = ((size_t)b * N_ + p) * 64;
    #pragma unroll 4
    for (int c = 0; c < 64; c++) {
        float xv = ldx<DT>(fea, fb + c);
        const float* w = wt0 + (3 + c) * 64;
        #pragma unroll
        for (int o = 0; o < 64; o++) acc[o] = fmaf(xv, w[o], acc[o]);
    }
    #pragma unroll
    for (int o = 0; o < 64; o++)
        yT[(size_t)o * NR + row] = f2bf(acc[o]);
}

// ---------------------------------------------------------------------------
// BN stats over 64-channel channel-major bf16 buffer (dtype-independent).
// ---------------------------------------------------------------------------
__global__ __launch_bounds__(256) void stats_pass(
        const ushort_t* __restrict__ y, float* __restrict__ part) {
    int cb = blockIdx.x;
    int c = cb >> 5, ch = cb & 31;
    size_t base = (size_t)c * NR + (size_t)ch * 16384;
    float s = 0.0f, q = 0.0f;
    for (int i = threadIdx.x; i < 16384; i += 256) {
        float v = bf2f(y[base + i]);
        s += v;
        q = fmaf(v, v, q);
    }
    __shared__ float ls[256], lq[256];
    int tid = threadIdx.x;
    ls[tid] = s; lq[tid] = q;
    __syncthreads();
    for (int off = 128; off >= 1; off >>= 1) {
        if (tid < off) { ls[tid] += ls[tid + off]; lq[tid] += lq[tid + off]; }
        __syncthreads();
    }
    if (tid == 0) { part[cb * 2 + 0] = ls[0]; part[cb * 2 + 1] = lq[0]; }
}

template <int DT>
__global__ __launch_bounds__(64) void stats_fin(
        const float* __restrict__ part, const void* __restrict__ g,
        const void* __restrict__ be, float* __restrict__ ab,
        const int* __restrict__ flag) {
    if (*flag != DT) return;
    int o = threadIdx.x;  // C = 64
    double s = 0.0, q = 0.0;
    for (int ch = 0; ch < 32; ch++) {
        s += (double)part[(o * 32 + ch) * 2 + 0];
        q += (double)part[(o * 32 + ch) * 2 + 1];
    }
    double mu = s / (double)NR;
    double var = q / (double)NR - mu * mu;
    if (var < 0.0) var = 0.0;
    double a = (double)ldx<DT>(g, o) / sqrt(var + 1e-5);
    ab[o]      = (float)a;
    ab[64 + o] = (float)((double)ldx<DT>(be, o) - mu * a);
}

// ---------------------------------------------------------------------------
// L1: in-place on yT. Each thread owns one row. (dtype-independent)
// ---------------------------------------------------------------------------
__global__ __launch_bounds__(256) void l1_kernel(
        ushort_t* yT, const float* __restrict__ wt1, const float* __restrict__ ab) {
    int row = blockIdx.x * 256 + threadIdx.x;
    float xv[64];
    #pragma unroll
    for (int c = 0; c < 64; c++)
        xv[c] = fmaxf(fmaf(bf2f(yT[(size_t)c * NR + row]), ab[c], ab[64 + c]), 0.0f);
    float acc[64];
    #pragma unroll
    for (int o = 0; o < 64; o++) acc[o] = 0.0f;
    #pragma unroll 4
    for (int c = 0; c < 64; c++) {
        #pragma unroll
        for (int o = 0; o < 64; o++) acc[o] = fmaf(xv[c], wt1[c * 64 + o], acc[o]);
    }
    #pragma unroll
    for (int o = 0; o < 64; o++)
        yT[(size_t)o * NR + row] = f2bf(acc[o]);
}

// ---------------------------------------------------------------------------
// L2 stats: recompute y2 on the fly, butterfly-reduce per wave. (independent)
// part2: sums [128][NWAVES], sumsq at +128*NWAVES.
// ---------------------------------------------------------------------------
__global__ __launch_bounds__(256) void l2s_kernel(
        const ushort_t* __restrict__ yT, const float* __restrict__ wt2,
        const float* __restrict__ ab1, float* __restrict__ part2) {
    int row = blockIdx.x * 256 + threadIdx.x;
    int half = blockIdx.y;
    int lane = threadIdx.x & 63;
    int wv = blockIdx.x * 4 + (threadIdx.x >> 6);
    float xv[64];
    #pragma unroll
    for (int c = 0; c < 64; c++)
        xv[c] = fmaxf(fmaf(bf2f(yT[(size_t)c * NR + row]), ab1[c], ab1[64 + c]), 0.0f);
    const float* w = wt2 + half * 64;
    #pragma unroll 2
    for (int o = 0; o < 64; o++) {
        float a = 0.0f;
        #pragma unroll
        for (int c = 0; c < 64; c++) a = fmaf(xv[c], w[c * 128 + o], a);
        float s = a, q = a * a;
        #pragma unroll
        for (int m = 1; m <= 32; m <<= 1) { s += __shfl_xor(s, m); q += __shfl_xor(q, m); }
        if (lane == 0) {
            int og = half * 64 + o;
            part2[og * NWAVES + wv] = s;
            part2[128 * NWAVES + og * NWAVES + wv] = q;
        }
    }
}

template <int DT>
__global__ __launch_bounds__(256) void stats2_fin(
        const float* __restrict__ part2, const void* __restrict__ g,
        const void* __restrict__ be, float* __restrict__ ab2,
        const int* __restrict__ flag) {
    if (*flag != DT) return;
    int og = blockIdx.x;  // 0..127
    float s = 0.0f, q = 0.0f;
    for (int wv = threadIdx.x; wv < NWAVES; wv += 256) {
        s += part2[og * NWAVES + wv];
        q += part2[128 * NWAVES + og * NWAVES + wv];
    }
    __shared__ float ls[256], lq[256];
    int tid = threadIdx.x;
    ls[tid] = s; lq[tid] = q;
    __syncthreads();
    for (int off = 128; off >= 1; off >>= 1) {
        if (tid < off) { ls[tid] += ls[tid + off]; lq[tid] += lq[tid + off]; }
        __syncthreads();
    }
    if (tid == 0) {
        double mu = (double)ls[0] / (double)NR;
        double var = (double)lq[0] / (double)NR - mu * mu;
        if (var < 0.0) var = 0.0;
        double a = (double)ldx<DT>(g, og) / sqrt(var + 1e-5);
        ab2[og]       = (float)a;
        ab2[128 + og] = (float)((double)ldx<DT>(be, og) - mu * a);
    }
}

// ---------------------------------------------------------------------------
// fin: recompute y2, BN+ReLU, maxpool over K (butterfly max over 32 lanes).
// ---------------------------------------------------------------------------
template <int DT>
__global__ __launch_bounds__(256) void fin_kernel(
        const ushort_t* __restrict__ yT, const float* __restrict__ wt2,
        const float* __restrict__ ab1, const float* __restrict__ ab2,
        void* __restrict__ out, const int* __restrict__ flag) {
    if (*flag != DT) return;
    int row = blockIdx.x * 256 + threadIdx.x;
    int half = blockIdx.y;
    int k = row & 31, bs = row >> 5;
    float xv[64];
    #pragma unroll
    for (int c = 0; c < 64; c++)
        xv[c] = fmaxf(fmaf(bf2f(yT[(size_t)c * NR + row]), ab1[c], ab1[64 + c]), 0.0f);
    const float* w = wt2 + half * 64;
    #pragma unroll 2
    for (int o = 0; o < 64; o++) {
        float a = 0.0f;
        #pragma unroll
        for (int c = 0; c < 64; c++) a = fmaf(xv[c], w[c * 128 + o], a);
        int og = half * 64 + o;
        float v = fmaxf(fmaf(a, ab2[og], ab2[128 + og]), 0.0f);
        #pragma unroll
        for (int m = 1; m <= 16; m <<= 1) v = fmaxf(v, __shfl_xor(v, m));
        if (k == 0) stx<DT>(out, 49152 + (size_t)bs * 128 + og, v);
    }
}

// ---------------------------------------------------------------------------
extern "C" void kernel_launch(void* const* d_in, const int* in_sizes, int n_in,
                              void* d_out, int out_size, void* d_ws, size_t ws_size,
                              hipStream_t stream) {
    const void* xyz = d_in[0];
    const void* fea = d_in[1];
    const void* W0  = d_in[2];
    const void* g0  = d_in[4];
    const void* be0 = d_in[5];
    const void* W1  = d_in[6];
    const void* g1  = d_in[8];
    const void* be1 = d_in[9];
    const void* W2  = d_in[10];
    const void* g2  = d_in[12];
    const void* be2 = d_in[13];

    char* w = (char*)d_ws;
    // total workspace footprint: 77,875,972 B (~74.3 MB)
    ushort_t* yT   = (ushort_t*)(w);                       // 67,108,864
    int*      nbr  = (int*)     (w + 67108864);            //  2,097,152
    float*    qxyz = (float*)   (w + 69206016);            //    196,608
    float*    part = (float*)   (w + 69402624);            //     16,384
    float*    part2= (float*)   (w + 69419008);            //  8,388,608
    float*    ab0  = (float*)   (w + 77807616);            //        512
    float*    ab1  = (float*)   (w + 77808128);            //        512
    float*    ab2  = (float*)   (w + 77808640);            //      1,024
    float*    wt0  = (float*)   (w + 77809664);            //     17,152
    float*    wt1  = (float*)   (w + 77826816);            //     16,384
    float*    wt2  = (float*)   (w + 77843200);            //     32,768
    int*      flag = (int*)     (w + 77875968);            //          4

    detect_kernel<<<1, 64, 0, stream>>>((const uint_t*)xyz, flag);

    prep_kernel<DT_BF16><<<1, 256, 0, stream>>>(W0, W1, W2, wt0, wt1, wt2, flag);
    prep_kernel<DT_FP32><<<1, 256, 0, stream>>>(W0, W1, W2, wt0, wt1, wt2, flag);

    fps_kernel<DT_BF16><<<B_, 1024, 0, stream>>>(xyz, qxyz, d_out, flag);
    fps_kernel<DT_FP32><<<B_, 1024, 0, stream>>>(xyz, qxyz, d_out, flag);

    knn_kernel<DT_BF16><<<NQ, 64, 0, stream>>>(xyz, qxyz, nbr, flag);
    knn_kernel<DT_FP32><<<NQ, 64, 0, stream>>>(xyz, qxyz, nbr, flag);

    // layer 0
    l0_kernel<DT_BF16><<<2048, 256, 0, stream>>>(xyz, fea, qxyz, nbr, wt0, yT, flag);
    l0_kernel<DT_FP32><<<2048, 256, 0, stream>>>(xyz, fea, qxyz, nbr, wt0, yT, flag);
    stats_pass<<<64 * 32, 256, 0, stream>>>(yT, part);
    stats_fin<DT_BF16><<<1, 64, 0, stream>>>(part, g0, be0, ab0, flag);
    stats_fin<DT_FP32><<<1, 64, 0, stream>>>(part, g0, be0, ab0, flag);

    // layer 1 (in-place)
    l1_kernel<<<2048, 256, 0, stream>>>(yT, wt1, ab0);
    stats_pass<<<64 * 32, 256, 0, stream>>>(yT, part);
    stats_fin<DT_BF16><<<1, 64, 0, stream>>>(part, g1, be1, ab1, flag);
    stats_fin<DT_FP32><<<1, 64, 0, stream>>>(part, g1, be1, ab1, flag);

    // layer 2: stats via recompute, then fused bn+relu+maxpool via recompute
    l2s_kernel<<<dim3(2048, 2), 256, 0, stream>>>(yT, wt2, ab1, part2);
    stats2_fin<DT_BF16><<<128, 256, 0, stream>>>(part2, g2, be2, ab2, flag);
    stats2_fin<DT_FP32><<<128, 256, 0, stream>>>(part2, g2, be2, ab2, flag);

    fin_kernel<DT_BF16><<<dim3(2048, 2), 256, 0, stream>>>(yT, wt2, ab1, ab2, d_out, flag);
    fin_kernel<DT_FP32><<<dim3(2048, 2), 256, 0, stream>>>(yT, wt2, ab1, ab2, d_out, flag);
}

// Round 4
// 2355.429 us; speedup vs baseline: 1.1510x; 1.1510x over previous
//
#include <hip/hip_runtime.h>
#include <cstdint>
#include <cstddef>

typedef unsigned short ushort_t;
typedef unsigned int uint_t;

#define B_ 16
#define N_ 4096
#define S_ 1024
#define K_ 32
#define NR 524288    // B*S*K rows
#define NQ 16384     // B*S queries
#define NWAVES 8192  // NR / 64

// DT: 1 = bf16 buffers, 0 = fp32 buffers
#define DT_BF16 1
#define DT_FP32 0

__device__ __forceinline__ float bf2f(ushort_t u) {
    union { uint_t i; float f; } x; x.i = ((uint_t)u) << 16; return x.f;
}
__device__ __forceinline__ ushort_t f2bf(float f) {
    union { float f; uint_t u; } x; x.f = f;
    uint_t u = x.u;
    uint_t r = (u + 0x7fffu + ((u >> 16) & 1u)) >> 16;   // RNE
    return (ushort_t)r;
}

template <int DT>
__device__ __forceinline__ float ldx(const void* p, size_t i) {
    if (DT) return bf2f(((const ushort_t*)p)[i]);
    else    return ((const float*)p)[i];
}
template <int DT>
__device__ __forceinline__ void stx(void* p, size_t i, float v) {
    if (DT) ((ushort_t*)p)[i] = f2bf(v);
    else    ((float*)p)[i] = v;
}

// ---------------------------------------------------------------------------
// detect: bf16 (flag=1) vs fp32 (flag=0) inputs, from exponent-field stats.
// ---------------------------------------------------------------------------
__global__ void detect_kernel(const uint_t* __restrict__ xyz, int* __restrict__ flag) {
    if (threadIdx.x == 0 && blockIdx.x == 0) {
        int hits = 0;
        for (int i = 0; i < 256; i++) {
            uint_t lo = xyz[i] & 0xffffu;
            int e = (int)((lo >> 7) & 0xffu);
            if (e >= 117 && e <= 131) hits++;
        }
        *flag = (hits >= 128) ? 1 : 0;
    }
}

// ---------------------------------------------------------------------------
// prep: weights -> fp32 transposed. wt0[c][64], wt1[c][64], wt2[c][128]
// ---------------------------------------------------------------------------
template <int DT>
__global__ __launch_bounds__(256) void prep_kernel(
        const void* __restrict__ W0, const void* __restrict__ W1,
        const void* __restrict__ W2,
        float* __restrict__ wt0, float* __restrict__ wt1, float* __restrict__ wt2,
        const int* __restrict__ flag) {
    if (*flag != DT) return;
    int tid = threadIdx.x;
    for (int i = tid; i < 64 * 67; i += 256) { int o = i / 67, c = i % 67; wt0[c * 64 + o] = ldx<DT>(W0, i); }
    for (int i = tid; i < 64 * 64; i += 256) { int o = i >> 6, c = i & 63; wt1[c * 64 + o] = ldx<DT>(W1, i); }
    for (int i = tid; i < 128 * 64; i += 256) { int o = i >> 6, c = i & 63; wt2[c * 128 + o] = ldx<DT>(W2, i); }
}

// ---------------------------------------------------------------------------
// FPS: one block (256 thr = 4 waves) per batch, 16 pts/thread in VGPRs.
// One barrier per iteration (double-buffered candidate slots); every thread
// redundantly finalizes the 4-way argmax. Exact ref arithmetic, first-index
// tie-break (np.argmax semantics).
// ---------------------------------------------------------------------------
template <int DT>
__global__ __launch_bounds__(256) void fps_kernel(
        const void* __restrict__ xyz, float* __restrict__ qxyz,
        void* __restrict__ out_sxyz, const int* __restrict__ flag) {
    #pragma clang fp contract(off)
    if (*flag != DT) return;
    __shared__ float xs[N_], ys[N_], zs[N_];
    __shared__ float cv[2][4];
    __shared__ int   ci[2][4];
    int b = blockIdx.x, tid = threadIdx.x;
    int wv = tid >> 6, lane = tid & 63;
    size_t base = (size_t)b * N_ * 3;

    float px[16], py[16], pz[16], dist[16];
    #pragma unroll
    for (int t = 0; t < 16; t++) {
        int p = tid + t * 256;
        float x = ldx<DT>(xyz, base + p * 3 + 0);
        float y = ldx<DT>(xyz, base + p * 3 + 1);
        float z = ldx<DT>(xyz, base + p * 3 + 2);
        px[t] = x; py[t] = y; pz[t] = z;
        xs[p] = x; ys[p] = y; zs[p] = z;
        dist[t] = 1e10f;
    }
    __syncthreads();

    int far = 0;
    for (int i = 0; i < S_; i++) {
        float cx = xs[far], cy = ys[far], cz = zs[far];
        if (tid == 0) {
            int qi = b * S_ + i;
            qxyz[qi * 3 + 0] = cx; qxyz[qi * 3 + 1] = cy; qxyz[qi * 3 + 2] = cz;
            stx<DT>(out_sxyz, (size_t)qi * 3 + 0, cx);
            stx<DT>(out_sxyz, (size_t)qi * 3 + 1, cy);
            stx<DT>(out_sxyz, (size_t)qi * 3 + 2, cz);
        }
        float bv = -1.0f; int bi = 0x7fffffff;
        #pragma unroll
        for (int t = 0; t < 16; t++) {
            float dx = px[t] - cx, dy = py[t] - cy, dz = pz[t] - cz;
            float d = (dx * dx + dy * dy) + dz * dz;   // matches ref sum order
            float nd = fminf(dist[t], d);
            dist[t] = nd;
            if (nd > bv) { bv = nd; bi = tid + t * 256; }   // strict >: first wins
        }
        #pragma unroll
        for (int off = 32; off >= 1; off >>= 1) {
            float ov = __shfl_down(bv, off);
            int   oi = __shfl_down(bi, off);
            if (ov > bv || (ov == bv && oi < bi)) { bv = ov; bi = oi; }
        }
        int buf = i & 1;
        if (lane == 0) { cv[buf][wv] = bv; ci[buf][wv] = bi; }
        __syncthreads();
        float fv = cv[buf][0]; int fi = ci[buf][0];
        #pragma unroll
        for (int w2 = 1; w2 < 4; w2++) {
            float ov = cv[buf][w2]; int oi = ci[buf][w2];
            if (ov > fv || (ov == fv && oi < fi)) { fv = ov; fi = oi; }
        }
        far = fi;
    }
}

// ---------------------------------------------------------------------------
// KNN: one wave per query -> 32 neighbor indices. Exact reference distance.
// ---------------------------------------------------------------------------
template <int DT>
__global__ __launch_bounds__(64) void knn_kernel(
        const void* __restrict__ xyz, const float* __restrict__ qxyz,
        int* __restrict__ nbr, const int* __restrict__ flag) {
    #pragma clang fp contract(off)
    if (*flag != DT) return;
    __shared__ float dsm[N_];
    int bs = blockIdx.x;
    int b = bs >> 10;
    int lane = threadIdx.x;
    size_t xb = (size_t)b * N_ * 3;

    float qx = qxyz[bs * 3 + 0], qy = qxyz[bs * 3 + 1], qz = qxyz[bs * 3 + 2];
    float qq = (qx * qx + qy * qy) + qz * qz;

    const float FINF = __builtin_inff();
    float lv = FINF; int li = 0;
    for (int s = 0; s < 64; s++) {
        int p = s * 64 + lane;
        float x = ldx<DT>(xyz, xb + p * 3 + 0);
        float y = ldx<DT>(xyz, xb + p * 3 + 1);
        float z = ldx<DT>(xyz, xb + p * 3 + 2);
        float pp = (x * x + y * y) + z * z;
        float dt = (qx * x + qy * y) + qz * z;
        float d = (qq + pp) - 2.0f * dt;               // matches ref
        dsm[s * 64 + ((lane + s) & 63)] = d;           // swizzled store
        if (d < lv) { lv = d; li = p; }
    }
    __syncthreads();

    unsigned long long mask = 0ull;   // consumed rows of MY column
    int my_nbr = 0;
    for (int r = 0; r < K_; r++) {
        float v = lv; int idx = li;
        #pragma unroll
        for (int off = 32; off >= 1; off >>= 1) {
            float ov = __shfl_down(v, off);
            int   oi = __shfl_down(idx, off);
            if (ov < v || (ov == v && oi < idx)) { v = ov; idx = oi; }
        }
        idx = __shfl(idx, 0);
        int glane = idx & 63;
        if (lane == r) my_nbr = idx;
        if (lane == glane) mask |= 1ull << (idx >> 6);
        unsigned long long gm = __shfl(mask, glane);
        // refresh glane's column min over unconsumed entries (lane = s index)
        float v2 = ((gm >> lane) & 1ull) ? FINF : dsm[lane * 64 + ((glane + lane) & 63)];
        int i2 = lane * 64 + glane;
        #pragma unroll
        for (int off = 32; off >= 1; off >>= 1) {
            float ov = __shfl_down(v2, off);
            int   oi = __shfl_down(i2, off);
            if (ov < v2 || (ov == v2 && oi < i2)) { v2 = ov; i2 = oi; }
        }
        v2 = __shfl(v2, 0); i2 = __shfl(i2, 0);
        if (lane == glane) { lv = v2; li = i2; }
    }
    if (lane < K_) nbr[bs * K_ + lane] = my_nbr;
}

// ---------------------------------------------------------------------------
// L0: one thread per row. Vectorized feature gather + 67x64 FMA -> yT bf16.
// ---------------------------------------------------------------------------
template <int DT>
__global__ __launch_bounds__(256) void l0_kernel(
        const void* __restrict__ xyz, const void* __restrict__ fea,
        const float* __restrict__ qxyz, const int* __restrict__ nbr,
        const float* __restrict__ wt0, ushort_t* __restrict__ yT,
        const int* __restrict__ flag) {
    if (*flag != DT) return;
    int row = blockIdx.x * 256 + threadIdx.x;
    int bs = row >> 5, b = bs >> 10;
    int p = nbr[row];
    p = (p < 0) ? 0 : (p > N_ - 1 ? N_ - 1 : p);       // defensive clamp
    float qx = qxyz[bs * 3 + 0], qy = qxyz[bs * 3 + 1], qz = qxyz[bs * 3 + 2];
    size_t xb = ((size_t)b * N_ + p) * 3;
    float dx = ldx<DT>(xyz, xb + 0) - qx;
    float dy = ldx<DT>(xyz, xb + 1) - qy;
    float dz = ldx<DT>(xyz, xb + 2) - qz;

    float acc[64];
    #pragma unroll
    for (int o = 0; o < 64; o++)
        acc[o] = fmaf(dz, wt0[128 + o], fmaf(dy, wt0[64 + o], dx * wt0[o]));

    size_t fb = ((size_t)b * N_ + p) * 64;
    if (DT) {
        const uint4* fr = (const uint4*)((const ushort_t*)fea + fb);
        #pragma unroll 2
        for (int i = 0; i < 8; i++) {
            uint4 u = fr[i];
            uint_t ua[4] = { u.x, u.y, u.z, u.w };
            #pragma unroll
            for (int j = 0; j < 4; j++) {
                float x0 = bf2f((ushort_t)(ua[j] & 0xffffu));
                float x1 = bf2f((ushort_t)(ua[j] >> 16));
                const float* w = wt0 + (3 + i * 8 + j * 2) * 64;
                #pragma unroll
                for (int o = 0; o < 64; o++) acc[o] = fmaf(x0, w[o], acc[o]);
                #pragma unroll
                for (int o = 0; o < 64; o++) acc[o] = fmaf(x1, w[64 + o], acc[o]);
            }
        }
    } else {
        const float4* fr = (const float4*)((const float*)fea + fb);
        #pragma unroll 2
        for (int i = 0; i < 16; i++) {
            float4 u = fr[i];
            float ua[4] = { u.x, u.y, u.z, u.w };
            #pragma unroll
            for (int j = 0; j < 4; j++) {
                const float* w = wt0 + (3 + i * 4 + j) * 64;
                #pragma unroll
                for (int o = 0; o < 64; o++) acc[o] = fmaf(ua[j], w[o], acc[o]);
            }
        }
    }
    #pragma unroll
    for (int o = 0; o < 64; o++)
        yT[(size_t)o * NR + row] = f2bf(acc[o]);
}

// ---------------------------------------------------------------------------
// BN stats over 64-channel channel-major bf16 buffer (dtype-independent).
// ---------------------------------------------------------------------------
__global__ __launch_bounds__(256) void stats_pass(
        const ushort_t* __restrict__ y, float* __restrict__ part) {
    int cb = blockIdx.x;
    int c = cb >> 5, ch = cb & 31;
    size_t base = (size_t)c * NR + (size_t)ch * 16384;
    float s = 0.0f, q = 0.0f;
    for (int i = threadIdx.x; i < 16384; i += 256) {
        float v = bf2f(y[base + i]);
        s += v;
        q = fmaf(v, v, q);
    }
    __shared__ float ls[256], lq[256];
    int tid = threadIdx.x;
    ls[tid] = s; lq[tid] = q;
    __syncthreads();
    for (int off = 128; off >= 1; off >>= 1) {
        if (tid < off) { ls[tid] += ls[tid + off]; lq[tid] += lq[tid + off]; }
        __syncthreads();
    }
    if (tid == 0) { part[cb * 2 + 0] = ls[0]; part[cb * 2 + 1] = lq[0]; }
}

template <int DT>
__global__ __launch_bounds__(64) void stats_fin(
        const float* __restrict__ part, const void* __restrict__ g,
        const void* __restrict__ be, float* __restrict__ ab,
        const int* __restrict__ flag) {
    if (*flag != DT) return;
    int o = threadIdx.x;  // C = 64
    double s = 0.0, q = 0.0;
    for (int ch = 0; ch < 32; ch++) {
        s += (double)part[(o * 32 + ch) * 2 + 0];
        q += (double)part[(o * 32 + ch) * 2 + 1];
    }
    double mu = s / (double)NR;
    double var = q / (double)NR - mu * mu;
    if (var < 0.0) var = 0.0;
    double a = (double)ldx<DT>(g, o) / sqrt(var + 1e-5);
    ab[o]      = (float)a;
    ab[64 + o] = (float)((double)ldx<DT>(be, o) - mu * a);
}

// ---------------------------------------------------------------------------
// L1: in-place on yT. Each thread owns one row. (dtype-independent)
// ---------------------------------------------------------------------------
__global__ __launch_bounds__(256) void l1_kernel(
        ushort_t* yT, const float* __restrict__ wt1, const float* __restrict__ ab) {
    int row = blockIdx.x * 256 + threadIdx.x;
    float xv[64];
    #pragma unroll
    for (int c = 0; c < 64; c++)
        xv[c] = fmaxf(fmaf(bf2f(yT[(size_t)c * NR + row]), ab[c], ab[64 + c]), 0.0f);
    float acc[64];
    #pragma unroll
    for (int o = 0; o < 64; o++) acc[o] = 0.0f;
    #pragma unroll 4
    for (int c = 0; c < 64; c++) {
        #pragma unroll
        for (int o = 0; o < 64; o++) acc[o] = fmaf(xv[c], wt1[c * 64 + o], acc[o]);
    }
    #pragma unroll
    for (int o = 0; o < 64; o++)
        yT[(size_t)o * NR + row] = f2bf(acc[o]);
}

// ---------------------------------------------------------------------------
// L2 stats: recompute y2 on the fly, butterfly-reduce per wave. (independent)
// part2: sums [128][NWAVES], sumsq at +128*NWAVES.
// ---------------------------------------------------------------------------
__global__ __launch_bounds__(256) void l2s_kernel(
        const ushort_t* __restrict__ yT, const float* __restrict__ wt2,
        const float* __restrict__ ab1, float* __restrict__ part2) {
    int row = blockIdx.x * 256 + threadIdx.x;
    int half = blockIdx.y;
    int lane = threadIdx.x & 63;
    int wv = blockIdx.x * 4 + (threadIdx.x >> 6);
    float xv[64];
    #pragma unroll
    for (int c = 0; c < 64; c++)
        xv[c] = fmaxf(fmaf(bf2f(yT[(size_t)c * NR + row]), ab1[c], ab1[64 + c]), 0.0f);
    const float* w = wt2 + half * 64;
    #pragma unroll 2
    for (int o = 0; o < 64; o++) {
        float a = 0.0f;
        #pragma unroll
        for (int c = 0; c < 64; c++) a = fmaf(xv[c], w[c * 128 + o], a);
        float s = a, q = a * a;
        #pragma unroll
        for (int m = 1; m <= 32; m <<= 1) { s += __shfl_xor(s, m); q += __shfl_xor(q, m); }
        if (lane == 0) {
            int og = half * 64 + o;
            part2[og * NWAVES + wv] = s;
            part2[128 * NWAVES + og * NWAVES + wv] = q;
        }
    }
}

template <int DT>
__global__ __launch_bounds__(256) void stats2_fin(
        const float* __restrict__ part2, const void* __restrict__ g,
        const void* __restrict__ be, float* __restrict__ ab2,
        const int* __restrict__ flag) {
    if (*flag != DT) return;
    int og = blockIdx.x;  // 0..127
    float s = 0.0f, q = 0.0f;
    for (int wv = threadIdx.x; wv < NWAVES; wv += 256) {
        s += part2[og * NWAVES + wv];
        q += part2[128 * NWAVES + og * NWAVES + wv];
    }
    __shared__ float ls[256], lq[256];
    int tid = threadIdx.x;
    ls[tid] = s; lq[tid] = q;
    __syncthreads();
    for (int off = 128; off >= 1; off >>= 1) {
        if (tid < off) { ls[tid] += ls[tid + off]; lq[tid] += lq[tid + off]; }
        __syncthreads();
    }
    if (tid == 0) {
        double mu = (double)ls[0] / (double)NR;
        double var = (double)lq[0] / (double)NR - mu * mu;
        if (var < 0.0) var = 0.0;
        double a = (double)ldx<DT>(g, og) / sqrt(var + 1e-5);
        ab2[og]       = (float)a;
        ab2[128 + og] = (float)((double)ldx<DT>(be, og) - mu * a);
    }
}

// ---------------------------------------------------------------------------
// fin: recompute y2, BN+ReLU, maxpool over K (butterfly max over 32 lanes).
// ---------------------------------------------------------------------------
template <int DT>
__global__ __launch_bounds__(256) void fin_kernel(
        const ushort_t* __restrict__ yT, const float* __restrict__ wt2,
        const float* __restrict__ ab1, const float* __restrict__ ab2,
        void* __restrict__ out, const int* __restrict__ flag) {
    if (*flag != DT) return;
    int row = blockIdx.x * 256 + threadIdx.x;
    int half = blockIdx.y;
    int k = row & 31, bs = row >> 5;
    float xv[64];
    #pragma unroll
    for (int c = 0; c < 64; c++)
        xv[c] = fmaxf(fmaf(bf2f(yT[(size_t)c * NR + row]), ab1[c], ab1[64 + c]), 0.0f);
    const float* w = wt2 + half * 64;
    #pragma unroll 2
    for (int o = 0; o < 64; o++) {
        float a = 0.0f;
        #pragma unroll
        for (int c = 0; c < 64; c++) a = fmaf(xv[c], w[c * 128 + o], a);
        int og = half * 64 + o;
        float v = fmaxf(fmaf(a, ab2[og], ab2[128 + og]), 0.0f);
        #pragma unroll
        for (int m = 1; m <= 16; m <<= 1) v = fmaxf(v, __shfl_xor(v, m));
        if (k == 0) stx<DT>(out, 49152 + (size_t)bs * 128 + og, v);
    }
}

// ---------------------------------------------------------------------------
extern "C" void kernel_launch(void* const* d_in, const int* in_sizes, int n_in,
                              void* d_out, int out_size, void* d_ws, size_t ws_size,
                              hipStream_t stream) {
    const void* xyz = d_in[0];
    const void* fea = d_in[1];
    const void* W0  = d_in[2];
    const void* g0  = d_in[4];
    const void* be0 = d_in[5];
    const void* W1  = d_in[6];
    const void* g1  = d_in[8];
    const void* be1 = d_in[9];
    const void* W2  = d_in[10];
    const void* g2  = d_in[12];
    const void* be2 = d_in[13];

    char* w = (char*)d_ws;
    // total workspace footprint: 77,875,972 B (~74.3 MB)
    ushort_t* yT   = (ushort_t*)(w);                       // 67,108,864
    int*      nbr  = (int*)     (w + 67108864);            //  2,097,152
    float*    qxyz = (float*)   (w + 69206016);            //    196,608
    float*    part = (float*)   (w + 69402624);            //     16,384
    float*    part2= (float*)   (w + 69419008);            //  8,388,608
    float*    ab0  = (float*)   (w + 77807616);            //        512
    float*    ab1  = (float*)   (w + 77808128);            //        512
    float*    ab2  = (float*)   (w + 77808640);            //      1,024
    float*    wt0  = (float*)   (w + 77809664);            //     17,152
    float*    wt1  = (float*)   (w + 77826816);            //     16,384
    float*    wt2  = (float*)   (w + 77843200);            //     32,768
    int*      flag = (int*)     (w + 77875968);            //          4

    detect_kernel<<<1, 64, 0, stream>>>((const uint_t*)xyz, flag);

    prep_kernel<DT_BF16><<<1, 256, 0, stream>>>(W0, W1, W2, wt0, wt1, wt2, flag);
    prep_kernel<DT_FP32><<<1, 256, 0, stream>>>(W0, W1, W2, wt0, wt1, wt2, flag);

    fps_kernel<DT_BF16><<<B_, 256, 0, stream>>>(xyz, qxyz, d_out, flag);
    fps_kernel<DT_FP32><<<B_, 256, 0, stream>>>(xyz, qxyz, d_out, flag);

    knn_kernel<DT_BF16><<<NQ, 64, 0, stream>>>(xyz, qxyz, nbr, flag);
    knn_kernel<DT_FP32><<<NQ, 64, 0, stream>>>(xyz, qxyz, nbr, flag);

    // layer 0
    l0_kernel<DT_BF16><<<2048, 256, 0, stream>>>(xyz, fea, qxyz, nbr, wt0, yT, flag);
    l0_kernel<DT_FP32><<<2048, 256, 0, stream>>>(xyz, fea, qxyz, nbr, wt0, yT, flag);
    stats_pass<<<64 * 32, 256, 0, stream>>>(yT, part);
    stats_fin<DT_BF16><<<1, 64, 0, stream>>>(part, g0, be0, ab0, flag);
    stats_fin<DT_FP32><<<1, 64, 0, stream>>>(part, g0, be0, ab0, flag);

    // layer 1 (in-place)
    l1_kernel<<<2048, 256, 0, stream>>>(yT, wt1, ab0);
    stats_pass<<<64 * 32, 256, 0, stream>>>(yT, part);
    stats_fin<DT_BF16><<<1, 64, 0, stream>>>(part, g1, be1, ab1, flag);
    stats_fin<DT_FP32><<<1, 64, 0, stream>>>(part, g1, be1, ab1, flag);

    // layer 2: stats via recompute, then fused bn+relu+maxpool via recompute
    l2s_kernel<<<dim3(2048, 2), 256, 0, stream>>>(yT, wt2, ab1, part2);
    stats2_fin<DT_BF16><<<128, 256, 0, stream>>>(part2, g2, be2, ab2, flag);
    stats2_fin<DT_FP32><<<128, 256, 0, stream>>>(part2, g2, be2, ab2, flag);

    fin_kernel<DT_BF16><<<dim3(2048, 2), 256, 0, stream>>>(yT, wt2, ab1, ab2, d_out, flag);
    fin_kernel<DT_FP32><<<dim3(2048, 2), 256, 0, stream>>>(yT, wt2, ab1, ab2, d_out, flag);
}